// Round 1
// baseline (562.979 us; speedup 1.0000x reference)
//
#include <hip/hip_runtime.h>

#define N_NODES 20000
#define N_EDGES 640000
#define HIDDEN  64
#define BATCH   8

// ---------------- kernels ----------------

// Accumulate weighted in-degree: deg[col[e]] += ew[e]
__global__ void k_deg(const int* __restrict__ col, const float* __restrict__ ew,
                      float* __restrict__ deg, int E) {
    int e = blockIdx.x * blockDim.x + threadIdx.x;
    if (e >= E) return;
    atomicAdd(&deg[col[e]], ew[e]);
}

// deg -> dis = 1/sqrt(deg + 1)   (self-loop weight 1; deg+1 >= 1 so no zero guard needed)
__global__ void k_dis(float* __restrict__ deg_dis, int N) {
    int n = blockIdx.x * blockDim.x + threadIdx.x;
    if (n >= N) return;
    float d = deg_dis[n] + 1.0f;
    deg_dis[n] = 1.0f / sqrtf(d);
}

// Pass 1: s1[b, col] += norm(e) * x[b, row]   for all 8 batches
__global__ void k_pass1(const int* __restrict__ row, const int* __restrict__ col,
                        const float* __restrict__ ew, const float* __restrict__ dis,
                        const float* __restrict__ x, float* __restrict__ s1, int E, int N) {
    int e = blockIdx.x * blockDim.x + threadIdx.x;
    if (e >= E) return;
    int r = row[e], c = col[e];
    float nr = dis[r] * ew[e] * dis[c];
#pragma unroll
    for (int b = 0; b < BATCH; ++b)
        atomicAdd(&s1[b * N + c], nr * x[b * N + r]);
}

// Per (b,n): finish s1 with self-loop, fold the 1->64->1 MLP to scalar t,
// and initialize out with x + 0.5*(b2 + self-loop term of pass 2).
__global__ void k_node(const float* __restrict__ x, const float* __restrict__ s1,
                       const float* __restrict__ dis,
                       const float* __restrict__ W1, const float* __restrict__ b1,
                       const float* __restrict__ W2, const float* __restrict__ b2,
                       float* __restrict__ t, float* __restrict__ out, int N) {
    int i = blockIdx.x * blockDim.x + threadIdx.x;   // i = b*N + n
    if (i >= BATCH * N) return;
    int n = i % N;
    float di = dis[n];
    float d2 = di * di;
    float s = s1[i] + d2 * x[i];
    float acc = 0.0f;
#pragma unroll
    for (int f = 0; f < HIDDEN; ++f) {
        float h = fmaf(s, W1[f], b1[f]);
        h = fmaxf(h, 0.0f);
        acc = fmaf(h, W2[f], acc);
    }
    t[i] = acc;
    out[i] = x[i] + 0.5f * (b2[0] + d2 * acc);
}

// Pass 2: out[b, col] += 0.5 * norm(e) * t[b, row]
__global__ void k_pass2(const int* __restrict__ row, const int* __restrict__ col,
                        const float* __restrict__ ew, const float* __restrict__ dis,
                        const float* __restrict__ t, float* __restrict__ out, int E, int N) {
    int e = blockIdx.x * blockDim.x + threadIdx.x;
    if (e >= E) return;
    int r = row[e], c = col[e];
    float nr = 0.5f * dis[r] * ew[e] * dis[c];
#pragma unroll
    for (int b = 0; b < BATCH; ++b)
        atomicAdd(&out[b * N + c], nr * t[b * N + r]);
}

// ---------------- launch ----------------

extern "C" void kernel_launch(void* const* d_in, const int* in_sizes, int n_in,
                              void* d_out, int out_size, void* d_ws, size_t ws_size,
                              hipStream_t stream) {
    const float* x  = (const float*)d_in[0];
    const int*   ei = (const int*)d_in[1];      // [2, E] int32 (JAX canonicalizes int64)
    const float* ew = (const float*)d_in[2];
    const float* W1 = (const float*)d_in[3];    // [1, 64]
    const float* b1 = (const float*)d_in[4];    // [64]
    const float* W2 = (const float*)d_in[5];    // [64, 1]
    const float* b2 = (const float*)d_in[6];    // [1]
    float* out = (float*)d_out;

    const int N = N_NODES, E = N_EDGES;
    const int* row = ei;
    const int* col = ei + E;

    float* ws  = (float*)d_ws;
    float* dis = ws;             // N floats (deg accumulator, then dis in-place)
    float* s1  = ws + N;         // BATCH*N floats
    float* t   = ws + N + BATCH * N; // BATCH*N floats

    // zero deg + s1 (must re-init every call; harness does not re-poison)
    hipMemsetAsync(d_ws, 0, (size_t)(N + BATCH * N) * sizeof(float), stream);

    const int BS = 256;
    int gE = (E + BS - 1) / BS;
    int gN = (N + BS - 1) / BS;
    int gBN = (BATCH * N + BS - 1) / BS;

    k_deg  <<<gE,  BS, 0, stream>>>(col, ew, dis, E);
    k_dis  <<<gN,  BS, 0, stream>>>(dis, N);
    k_pass1<<<gE,  BS, 0, stream>>>(row, col, ew, dis, x, s1, E, N);
    k_node <<<gBN, BS, 0, stream>>>(x, s1, dis, W1, b1, W2, b2, t, out, N);
    k_pass2<<<gE,  BS, 0, stream>>>(row, col, ew, dis, t, out, E, N);
}

// Round 2
// 246.620 us; speedup vs baseline: 2.2828x; 2.2828x over previous
//
#include <hip/hip_runtime.h>

#define N_NODES 20000
#define N_EDGES 640000
#define HIDDEN  64
#define BATCH   8

// ---- 1. histogram: cnt[col]++ ; deg[col] += ew ----
__global__ void k_hist(const int* __restrict__ col, const float* __restrict__ ew,
                       int* __restrict__ cnt, float* __restrict__ deg, int E) {
    int e = blockIdx.x * blockDim.x + threadIdx.x;
    if (e >= E) return;
    int c = col[e];
    atomicAdd(&cnt[c], 1);
    atomicAdd(&deg[c], ew[e]);
}

// ---- 2. single-block scan: starts = exscan(cnt); cursor = starts; dis = rsqrt(deg+1) ----
__global__ void k_scan(const int* __restrict__ cnt, int* __restrict__ starts,
                       int* __restrict__ cursor,
                       const float* __restrict__ deg, float* __restrict__ dis, int N) {
    __shared__ int buf[256];
    __shared__ int carry_s;
    int tid = threadIdx.x;
    if (tid == 0) carry_s = 0;
    __syncthreads();
    for (int base = 0; base < N; base += 256) {
        int i = base + tid;
        int v = (i < N) ? cnt[i] : 0;
        if (i < N) dis[i] = rsqrtf(deg[i] + 1.0f);
        buf[tid] = v;
        __syncthreads();
        for (int off = 1; off < 256; off <<= 1) {
            int tv = (tid >= off) ? buf[tid - off] : 0;
            __syncthreads();
            buf[tid] += tv;
            __syncthreads();
        }
        int excl = buf[tid] - v;
        if (i < N) { int s = carry_s + excl; starts[i] = s; cursor[i] = s; }
        int total = buf[255];
        __syncthreads();
        if (tid == 0) carry_s += total;
        __syncthreads();
    }
    if (tid == 0) starts[N] = carry_s;   // == E
}

// ---- 3. transpose x [B][N] -> xT [N][B] ----
__global__ void k_xt(const float* __restrict__ x, float* __restrict__ xT, int N) {
    int i = blockIdx.x * blockDim.x + threadIdx.x;
    if (i >= N * BATCH) return;
    int n = i >> 3, b = i & 7;
    xT[i] = x[b * N + n];
}

// ---- 4. scatter edges into CSR buckets; precompute norm ----
__global__ void k_scatter(const int* __restrict__ row, const int* __restrict__ col,
                          const float* __restrict__ ew, const float* __restrict__ dis,
                          int* __restrict__ cursor,
                          int* __restrict__ srow, float* __restrict__ snorm, int E) {
    int e = blockIdx.x * blockDim.x + threadIdx.x;
    if (e >= E) return;
    int r = row[e], c = col[e];
    int pos = atomicAdd(&cursor[c], 1);
    srow[pos] = r;
    snorm[pos] = dis[r] * ew[e] * dis[c];
}

// ---- 5. gather pass 1 + fused 1->64->1 MLP fold -> t ----
__global__ void k_gather1(const int* __restrict__ starts, const int* __restrict__ srow,
                          const float* __restrict__ snorm, const float* __restrict__ xT,
                          const float* __restrict__ dis,
                          const float* __restrict__ W1, const float* __restrict__ b1,
                          const float* __restrict__ W2, const float* __restrict__ b2,
                          float* __restrict__ t, int N) {
    int i = blockIdx.x * blockDim.x + threadIdx.x;
    if (i >= N * BATCH) return;
    int n = i >> 3, b = i & 7;
    float s = 0.0f;
    int e1 = starts[n + 1];
    for (int j = starts[n]; j < e1; ++j)
        s = fmaf(snorm[j], xT[(srow[j] << 3) + b], s);
    float di = dis[n];
    s = fmaf(di * di, xT[i], s);          // self-loop
    float acc = 0.0f;
#pragma unroll
    for (int f = 0; f < HIDDEN; ++f) {
        float h = fmaf(s, W1[f], b1[f]);
        acc = fmaf(fmaxf(h, 0.0f), W2[f], acc);
    }
    t[i] = acc;
}

// ---- 6. gather pass 2 + fused epilogue -> out [B][N] ----
__global__ void k_gather2(const int* __restrict__ starts, const int* __restrict__ srow,
                          const float* __restrict__ snorm, const float* __restrict__ t,
                          const float* __restrict__ xT, const float* __restrict__ dis,
                          const float* __restrict__ b2, float* __restrict__ out, int N) {
    int i = blockIdx.x * blockDim.x + threadIdx.x;
    if (i >= N * BATCH) return;
    int n = i >> 3, b = i & 7;
    float g = 0.0f;
    int e1 = starts[n + 1];
    for (int j = starts[n]; j < e1; ++j)
        g = fmaf(snorm[j], t[(srow[j] << 3) + b], g);
    float di = dis[n];
    g = fmaf(di * di, t[i], g);           // self-loop
    out[b * N + n] = xT[i] + 0.5f * (b2[0] + g);
}

// ---------------- launch ----------------
extern "C" void kernel_launch(void* const* d_in, const int* in_sizes, int n_in,
                              void* d_out, int out_size, void* d_ws, size_t ws_size,
                              hipStream_t stream) {
    const float* x  = (const float*)d_in[0];
    const int*   ei = (const int*)d_in[1];      // [2, E] int32
    const float* ew = (const float*)d_in[2];
    const float* W1 = (const float*)d_in[3];
    const float* b1 = (const float*)d_in[4];
    const float* W2 = (const float*)d_in[5];
    const float* b2 = (const float*)d_in[6];
    float* out = (float*)d_out;

    const int N = N_NODES, E = N_EDGES;
    const int* row = ei;
    const int* col = ei + E;

    // workspace layout (~6.8 MB)
    int*   cnt    = (int*)d_ws;                  // N  (zeroed)
    float* deg    = (float*)(cnt + N);           // N  (zeroed)
    int*   starts = (int*)(deg + N);             // N+1
    int*   cursor = starts + N + 1;              // N
    float* dis    = (float*)(cursor + N);        // N
    int*   srow   = (int*)(dis + N);             // E
    float* snorm  = (float*)(srow + E);          // E
    float* xT     = snorm + E;                   // N*BATCH
    float* t      = xT + N * BATCH;              // N*BATCH

    hipMemsetAsync(d_ws, 0, (size_t)(2 * N) * sizeof(float), stream);

    const int BS = 256;
    int gE  = (E + BS - 1) / BS;
    int gBN = (N * BATCH + BS - 1) / BS;

    k_hist   <<<gE,  BS, 0, stream>>>(col, ew, cnt, deg, E);
    k_scan   <<<1,   BS, 0, stream>>>(cnt, starts, cursor, deg, dis, N);
    k_xt     <<<gBN, BS, 0, stream>>>(x, xT, N);
    k_scatter<<<gE,  BS, 0, stream>>>(row, col, ew, dis, cursor, srow, snorm, E);
    k_gather1<<<gBN, BS, 0, stream>>>(starts, srow, snorm, xT, dis, W1, b1, W2, b2, t, N);
    k_gather2<<<gBN, BS, 0, stream>>>(starts, srow, snorm, t, xT, dis, b2, out, N);
}

// Round 3
// 125.147 us; speedup vs baseline: 4.4985x; 1.9706x over previous
//
#include <hip/hip_runtime.h>

#define N_NODES 20000
#define N_EDGES 640000
#define HIDDEN  64
#define BATCH   8
#define NB_SCAN ((N_NODES + 255) / 256)   // 79 blocks

__device__ inline int wave_iscan(int v, int lane) {
#pragma unroll
    for (int off = 1; off < 64; off <<= 1) {
        int u = __shfl_up(v, off, 64);
        if (lane >= off) v += u;
    }
    return v;
}

// ---- 1. histogram: packed[col] += (1<<40) | fx(ew)  (count | fixed-point deg) ----
__global__ void k_hist(const int* __restrict__ col, const float* __restrict__ ew,
                       unsigned long long* __restrict__ packed, int E) {
    int e = blockIdx.x * blockDim.x + threadIdx.x;
    if (e >= E) return;
    int c = col[e];
    unsigned long long fx = (unsigned long long)(ew[e] * 16777216.0f + 0.5f); // 2^24 fixed point
    atomicAdd(&packed[c], (1ULL << 40) | fx);
}

// ---- 2a. per-block exclusive scan of counts; also dis = rsqrt(deg+1) ----
__global__ void k_scan1(const unsigned long long* __restrict__ packed,
                        int* __restrict__ pre, int* __restrict__ bsum,
                        float* __restrict__ dis, int N) {
    int tid = threadIdx.x;
    int i = blockIdx.x * 256 + tid;
    int lane = tid & 63, wid = tid >> 6;
    unsigned long long p = (i < N) ? packed[i] : 0ULL;
    int v = (int)(p >> 40);
    if (i < N) {
        float deg = (float)(p & 0xFFFFFFFFFFULL) * 5.9604644775390625e-8f; // 2^-24
        dis[i] = rsqrtf(deg + 1.0f);
    }
    int incl = wave_iscan(v, lane);
    __shared__ int ws[4];
    if (lane == 63) ws[wid] = incl;
    __syncthreads();
    if (tid == 0) {
        int r = 0;
#pragma unroll
        for (int w = 0; w < 4; ++w) { int s = ws[w]; ws[w] = r; r += s; }
    }
    __syncthreads();
    int excl = incl - v + ws[wid];
    if (i < N) pre[i] = excl;
    if (tid == 255) bsum[blockIdx.x] = excl + v;   // block total
}

// ---- 2b. scan the 79 block sums (one block, 2 waves) ----
__global__ void k_scan2(const int* __restrict__ bsum, int* __restrict__ boff,
                        int* __restrict__ starts) {
    int tid = threadIdx.x;   // 128 threads
    int lane = tid & 63, wid = tid >> 6;
    int v = (tid < NB_SCAN) ? bsum[tid] : 0;
    int incl = wave_iscan(v, lane);
    __shared__ int w0;
    if (wid == 0 && lane == 63) w0 = incl;
    __syncthreads();
    if (wid == 1) incl += w0;
    if (tid < NB_SCAN) boff[tid] = incl - v;
    if (tid == 0) starts[N_NODES] = N_EDGES;
}

// ---- 2c. add block offsets -> starts, cursor ----
__global__ void k_scan3(const int* __restrict__ pre, const int* __restrict__ boff,
                        int* __restrict__ starts, int* __restrict__ cursor, int N) {
    int i = blockIdx.x * 256 + threadIdx.x;
    if (i >= N) return;
    int s = pre[i] + boff[blockIdx.x];
    starts[i] = s;
    cursor[i] = s;
}

// ---- 3. transpose x [B][N] -> xT [N][B] ----
__global__ void k_xt(const float* __restrict__ x, float* __restrict__ xT, int N) {
    int i = blockIdx.x * blockDim.x + threadIdx.x;
    if (i >= N * BATCH) return;
    int n = i >> 3, b = i & 7;
    xT[i] = x[b * N + n];
}

// ---- 4. scatter edges into CSR buckets; precompute norm ----
__global__ void k_scatter(const int* __restrict__ row, const int* __restrict__ col,
                          const float* __restrict__ ew, const float* __restrict__ dis,
                          int* __restrict__ cursor,
                          int* __restrict__ srow, float* __restrict__ snorm, int E) {
    int e = blockIdx.x * blockDim.x + threadIdx.x;
    if (e >= E) return;
    int r = row[e], c = col[e];
    int pos = atomicAdd(&cursor[c], 1);
    srow[pos] = r;
    snorm[pos] = dis[r] * ew[e] * dis[c];
}

// ---- 5. gather pass 1 + fused 1->64->1 MLP fold -> t ----
__global__ void k_gather1(const int* __restrict__ starts, const int* __restrict__ srow,
                          const float* __restrict__ snorm, const float* __restrict__ xT,
                          const float* __restrict__ dis,
                          const float* __restrict__ W1, const float* __restrict__ b1,
                          const float* __restrict__ W2, const float* __restrict__ b2,
                          float* __restrict__ t, int N) {
    int i = blockIdx.x * blockDim.x + threadIdx.x;
    if (i >= N * BATCH) return;
    int n = i >> 3, b = i & 7;
    float s = 0.0f;
    int e1 = starts[n + 1];
    for (int j = starts[n]; j < e1; ++j)
        s = fmaf(snorm[j], xT[(srow[j] << 3) + b], s);
    float di = dis[n];
    s = fmaf(di * di, xT[i], s);          // self-loop
    float acc = 0.0f;
#pragma unroll
    for (int f = 0; f < HIDDEN; ++f) {
        float h = fmaf(s, W1[f], b1[f]);
        acc = fmaf(fmaxf(h, 0.0f), W2[f], acc);
    }
    t[i] = acc;
}

// ---- 6. gather pass 2 + fused epilogue -> out [B][N] ----
__global__ void k_gather2(const int* __restrict__ starts, const int* __restrict__ srow,
                          const float* __restrict__ snorm, const float* __restrict__ t,
                          const float* __restrict__ xT, const float* __restrict__ dis,
                          const float* __restrict__ b2, float* __restrict__ out, int N) {
    int i = blockIdx.x * blockDim.x + threadIdx.x;
    if (i >= N * BATCH) return;
    int n = i >> 3, b = i & 7;
    float g = 0.0f;
    int e1 = starts[n + 1];
    for (int j = starts[n]; j < e1; ++j)
        g = fmaf(snorm[j], t[(srow[j] << 3) + b], g);
    float di = dis[n];
    g = fmaf(di * di, t[i], g);           // self-loop
    out[b * N + n] = xT[i] + 0.5f * (b2[0] + g);
}

// ---------------- launch ----------------
extern "C" void kernel_launch(void* const* d_in, const int* in_sizes, int n_in,
                              void* d_out, int out_size, void* d_ws, size_t ws_size,
                              hipStream_t stream) {
    const float* x  = (const float*)d_in[0];
    const int*   ei = (const int*)d_in[1];      // [2, E] int32
    const float* ew = (const float*)d_in[2];
    const float* W1 = (const float*)d_in[3];
    const float* b1 = (const float*)d_in[4];
    const float* W2 = (const float*)d_in[5];
    const float* b2 = (const float*)d_in[6];
    float* out = (float*)d_out;

    const int N = N_NODES, E = N_EDGES;
    const int* row = ei;
    const int* col = ei + E;

    // workspace layout
    unsigned long long* packed = (unsigned long long*)d_ws;   // N ull (zeroed)
    int*   pre    = (int*)(packed + N);          // N
    int*   bsum   = pre + N;                     // 128
    int*   boff   = bsum + 128;                  // 128
    int*   starts = boff + 128;                  // N+1
    int*   cursor = starts + N + 1;              // N
    float* dis    = (float*)(cursor + N);        // N
    int*   srow   = (int*)(dis + N);             // E
    float* snorm  = (float*)(srow + E);          // E
    float* xT     = snorm + E;                   // N*BATCH
    float* t      = xT + N * BATCH;              // N*BATCH

    hipMemsetAsync(d_ws, 0, (size_t)N * sizeof(unsigned long long), stream);

    const int BS = 256;
    int gE  = (E + BS - 1) / BS;
    int gBN = (N * BATCH + BS - 1) / BS;

    k_hist   <<<gE,      BS,  0, stream>>>(col, ew, packed, E);
    k_scan1  <<<NB_SCAN, 256, 0, stream>>>(packed, pre, bsum, dis, N);
    k_scan2  <<<1,       128, 0, stream>>>(bsum, boff, starts);
    k_scan3  <<<NB_SCAN, 256, 0, stream>>>(pre, boff, starts, cursor, N);
    k_xt     <<<gBN,     BS,  0, stream>>>(x, xT, N);
    k_scatter<<<gE,      BS,  0, stream>>>(row, col, ew, dis, cursor, srow, snorm, E);
    k_gather1<<<gBN,     BS,  0, stream>>>(starts, srow, snorm, xT, dis, W1, b1, W2, b2, t, N);
    k_gather2<<<gBN,     BS,  0, stream>>>(starts, srow, snorm, t, xT, dis, b2, out, N);
}

// Round 4
// 116.602 us; speedup vs baseline: 4.8282x; 1.0733x over previous
//
#include <hip/hip_runtime.h>

#define N_NODES 20000
#define N_EDGES 640000
#define HIDDEN  64
#define BATCH   8
#define NB_SCAN ((N_NODES + 255) / 256)   // 79 blocks

typedef unsigned long long ull;

__device__ inline int wave_iscan(int v, int lane) {
#pragma unroll
    for (int off = 1; off < 64; off <<= 1) {
        int u = __shfl_up(v, off, 64);
        if (lane >= off) v += u;
    }
    return v;
}

// ---- 1. histogram: packed[col] += (1<<40) | fx(ew)  (count | fixed-point deg) ----
__global__ void k_hist(const int* __restrict__ col, const float* __restrict__ ew,
                       ull* __restrict__ packed, int E) {
    int e = blockIdx.x * blockDim.x + threadIdx.x;
    if (e >= E) return;
    int c = col[e];
    ull fx = (ull)(ew[e] * 16777216.0f + 0.5f); // 2^24 fixed point
    atomicAdd(&packed[c], (1ULL << 40) | fx);
}

// ---- 2a. per-block exclusive scan of counts; dis = rsqrt(deg+1); fused x->xT transpose ----
__global__ void k_scan1(const ull* __restrict__ packed,
                        int* __restrict__ pre, int* __restrict__ bsum,
                        float* __restrict__ dis,
                        const float* __restrict__ x, float* __restrict__ xT, int N) {
    int tid = threadIdx.x;
    int i = blockIdx.x * 256 + tid;
    int lane = tid & 63, wid = tid >> 6;
    ull p = (i < N) ? packed[i] : 0ULL;
    int v = (int)(p >> 40);
    if (i < N) {
        float deg = (float)(p & 0xFFFFFFFFFFULL) * 5.9604644775390625e-8f; // 2^-24
        dis[i] = rsqrtf(deg + 1.0f);
        float4 lo, hi;
        lo.x = x[0 * N + i]; lo.y = x[1 * N + i]; lo.z = x[2 * N + i]; lo.w = x[3 * N + i];
        hi.x = x[4 * N + i]; hi.y = x[5 * N + i]; hi.z = x[6 * N + i]; hi.w = x[7 * N + i];
        ((float4*)xT)[i * 2]     = lo;
        ((float4*)xT)[i * 2 + 1] = hi;
    }
    int incl = wave_iscan(v, lane);
    __shared__ int ws[4];
    if (lane == 63) ws[wid] = incl;
    __syncthreads();
    if (tid == 0) {
        int r = 0;
#pragma unroll
        for (int w = 0; w < 4; ++w) { int s = ws[w]; ws[w] = r; r += s; }
    }
    __syncthreads();
    int excl = incl - v + ws[wid];
    if (i < N) pre[i] = excl;
    if (tid == 255) bsum[blockIdx.x] = excl + v;   // block total
}

// ---- 2b. scan the 79 block sums (one block, 2 waves) ----
__global__ void k_scan2(const int* __restrict__ bsum, int* __restrict__ boff,
                        int* __restrict__ starts) {
    int tid = threadIdx.x;   // 128 threads
    int lane = tid & 63, wid = tid >> 6;
    int v = (tid < NB_SCAN) ? bsum[tid] : 0;
    int incl = wave_iscan(v, lane);
    __shared__ int w0;
    if (wid == 0 && lane == 63) w0 = incl;
    __syncthreads();
    if (wid == 1) incl += w0;
    if (tid < NB_SCAN) boff[tid] = incl - v;
    if (tid == 0) starts[N_NODES] = N_EDGES;
}

// ---- 2c. add block offsets -> starts, cursor ----
__global__ void k_scan3(const int* __restrict__ pre, const int* __restrict__ boff,
                        int* __restrict__ starts, int* __restrict__ cursor, int N) {
    int i = blockIdx.x * 256 + threadIdx.x;
    if (i >= N) return;
    int s = pre[i] + boff[blockIdx.x];
    starts[i] = s;
    cursor[i] = s;
}

// ---- 3. scatter edges into CSR buckets as packed (row, norm) 8B records ----
__global__ void k_scatter(const int* __restrict__ row, const int* __restrict__ col,
                          const float* __restrict__ ew, const float* __restrict__ dis,
                          int* __restrict__ cursor, ull* __restrict__ sedge, int E) {
    int e = blockIdx.x * blockDim.x + threadIdx.x;
    if (e >= E) return;
    int r = row[e], c = col[e];
    float nr = dis[r] * ew[e] * dis[c];
    int pos = atomicAdd(&cursor[c], 1);
    sedge[pos] = ((ull)(unsigned)r << 32) | (ull)__float_as_uint(nr);
}

// ---- 4. gather pass 1 + fused 1->64->1 MLP fold -> t ----
__global__ void k_gather1(const int* __restrict__ starts, const ull* __restrict__ sedge,
                          const float* __restrict__ xT, const float* __restrict__ dis,
                          const float* __restrict__ W1, const float* __restrict__ b1,
                          const float* __restrict__ W2, const float* __restrict__ b2,
                          float* __restrict__ t, int N) {
    int i = blockIdx.x * blockDim.x + threadIdx.x;
    if (i >= N * BATCH) return;
    int n = i >> 3, b = i & 7;
    float s = 0.0f;
    int e1 = starts[n + 1];
    for (int j = starts[n]; j < e1; ++j) {
        ull v = sedge[j];
        int r = (int)(v >> 32);
        float nr = __uint_as_float((unsigned)v);
        s = fmaf(nr, xT[(r << 3) + b], s);
    }
    float di = dis[n];
    s = fmaf(di * di, xT[i], s);          // self-loop
    float acc = 0.0f;
#pragma unroll
    for (int f = 0; f < HIDDEN; ++f) {
        float h = fmaf(s, W1[f], b1[f]);
        acc = fmaf(fmaxf(h, 0.0f), W2[f], acc);
    }
    t[i] = acc;
}

// ---- 5. gather pass 2 + fused epilogue -> out [B][N] ----
__global__ void k_gather2(const int* __restrict__ starts, const ull* __restrict__ sedge,
                          const float* __restrict__ t, const float* __restrict__ xT,
                          const float* __restrict__ dis, const float* __restrict__ b2,
                          float* __restrict__ out, int N) {
    int i = blockIdx.x * blockDim.x + threadIdx.x;
    if (i >= N * BATCH) return;
    int n = i >> 3, b = i & 7;
    float g = 0.0f;
    int e1 = starts[n + 1];
    for (int j = starts[n]; j < e1; ++j) {
        ull v = sedge[j];
        int r = (int)(v >> 32);
        float nr = __uint_as_float((unsigned)v);
        g = fmaf(nr, t[(r << 3) + b], g);
    }
    float di = dis[n];
    g = fmaf(di * di, t[i], g);           // self-loop
    out[b * N + n] = xT[i] + 0.5f * (b2[0] + g);
}

// ---------------- launch ----------------
extern "C" void kernel_launch(void* const* d_in, const int* in_sizes, int n_in,
                              void* d_out, int out_size, void* d_ws, size_t ws_size,
                              hipStream_t stream) {
    const float* x  = (const float*)d_in[0];
    const int*   ei = (const int*)d_in[1];      // [2, E] int32
    const float* ew = (const float*)d_in[2];
    const float* W1 = (const float*)d_in[3];
    const float* b1 = (const float*)d_in[4];
    const float* W2 = (const float*)d_in[5];
    const float* b2 = (const float*)d_in[6];
    float* out = (float*)d_out;

    const int N = N_NODES, E = N_EDGES;
    const int* row = ei;
    const int* col = ei + E;

    // workspace layout (8B-aligned chunks first)
    ull*   packed = (ull*)d_ws;                  // N ull (zeroed)
    ull*   sedge  = packed + N;                  // E ull
    float* xT     = (float*)(sedge + E);         // N*BATCH (16B aligned)
    float* t      = xT + N * BATCH;              // N*BATCH
    int*   pre    = (int*)(t + N * BATCH);       // N
    int*   bsum   = pre + N;                     // 128
    int*   boff   = bsum + 128;                  // 128
    int*   starts = boff + 128;                  // N+1
    int*   cursor = starts + N + 1;              // N
    float* dis    = (float*)(cursor + N);        // N

    hipMemsetAsync(d_ws, 0, (size_t)N * sizeof(ull), stream);

    const int BS = 256;
    int gE  = (E + BS - 1) / BS;
    int gBN = (N * BATCH + BS - 1) / BS;

    k_hist   <<<gE,      BS,  0, stream>>>(col, ew, packed, E);
    k_scan1  <<<NB_SCAN, 256, 0, stream>>>(packed, pre, bsum, dis, x, xT, N);
    k_scan2  <<<1,       128, 0, stream>>>(bsum, boff, starts);
    k_scan3  <<<NB_SCAN, 256, 0, stream>>>(pre, boff, starts, cursor, N);
    k_scatter<<<gE,      BS,  0, stream>>>(row, col, ew, dis, cursor, sedge, E);
    k_gather1<<<gBN,     BS,  0, stream>>>(starts, sedge, xT, dis, W1, b1, W2, b2, t, N);
    k_gather2<<<gBN,     BS,  0, stream>>>(starts, sedge, t, xT, dis, b2, out, N);
}

// Round 5
// 116.236 us; speedup vs baseline: 4.8434x; 1.0031x over previous
//
#include <hip/hip_runtime.h>

#define N_NODES 20000
#define N_EDGES 640000
#define HIDDEN  64
#define BATCH   8
#define NB_SCAN ((N_NODES + 255) / 256)   // 79 blocks

typedef unsigned long long ull;

__device__ inline int wave_iscan(int v, int lane) {
#pragma unroll
    for (int off = 1; off < 64; off <<= 1) {
        int u = __shfl_up(v, off, 64);
        if (lane >= off) v += u;
    }
    return v;
}

// ---- 0. zero the histogram accumulator (replaces pathologically slow rocclr fill) ----
__global__ void k_zero(ull* __restrict__ packed, int N) {
    int i = blockIdx.x * blockDim.x + threadIdx.x;
    if (i < N) packed[i] = 0ULL;
}

// ---- 1. histogram: packed[col] += (1<<40) | fx(ew)  (count | fixed-point deg) ----
__global__ void k_hist(const int* __restrict__ col, const float* __restrict__ ew,
                       ull* __restrict__ packed, int E) {
    int e = blockIdx.x * blockDim.x + threadIdx.x;
    if (e >= E) return;
    int c = col[e];
    ull fx = (ull)(ew[e] * 16777216.0f + 0.5f); // 2^24 fixed point
    atomicAdd(&packed[c], (1ULL << 40) | fx);
}

// ---- 2a. per-block exclusive scan of counts; dis = rsqrt(deg+1); fused x->xT transpose ----
__global__ void k_scan1(const ull* __restrict__ packed,
                        int* __restrict__ pre, int* __restrict__ bsum,
                        float* __restrict__ dis,
                        const float* __restrict__ x, float* __restrict__ xT, int N) {
    int tid = threadIdx.x;
    int i = blockIdx.x * 256 + tid;
    int lane = tid & 63, wid = tid >> 6;
    ull p = (i < N) ? packed[i] : 0ULL;
    int v = (int)(p >> 40);
    if (i < N) {
        float deg = (float)(p & 0xFFFFFFFFFFULL) * 5.9604644775390625e-8f; // 2^-24
        dis[i] = rsqrtf(deg + 1.0f);
        float4 lo, hi;
        lo.x = x[0 * N + i]; lo.y = x[1 * N + i]; lo.z = x[2 * N + i]; lo.w = x[3 * N + i];
        hi.x = x[4 * N + i]; hi.y = x[5 * N + i]; hi.z = x[6 * N + i]; hi.w = x[7 * N + i];
        ((float4*)xT)[i * 2]     = lo;
        ((float4*)xT)[i * 2 + 1] = hi;
    }
    int incl = wave_iscan(v, lane);
    __shared__ int ws[4];
    if (lane == 63) ws[wid] = incl;
    __syncthreads();
    if (tid == 0) {
        int r = 0;
#pragma unroll
        for (int w = 0; w < 4; ++w) { int s = ws[w]; ws[w] = r; r += s; }
    }
    __syncthreads();
    int excl = incl - v + ws[wid];
    if (i < N) pre[i] = excl;
    if (tid == 255) bsum[blockIdx.x] = excl + v;   // block total
}

// ---- 2b. scan the 79 block sums (one block, 2 waves) ----
__global__ void k_scan2(const int* __restrict__ bsum, int* __restrict__ boff,
                        int* __restrict__ starts) {
    int tid = threadIdx.x;   // 128 threads
    int lane = tid & 63, wid = tid >> 6;
    int v = (tid < NB_SCAN) ? bsum[tid] : 0;
    int incl = wave_iscan(v, lane);
    __shared__ int w0;
    if (wid == 0 && lane == 63) w0 = incl;
    __syncthreads();
    if (wid == 1) incl += w0;
    if (tid < NB_SCAN) boff[tid] = incl - v;
    if (tid == 0) starts[N_NODES] = N_EDGES;
}

// ---- 2c. add block offsets -> starts, cursor ----
__global__ void k_scan3(const int* __restrict__ pre, const int* __restrict__ boff,
                        int* __restrict__ starts, int* __restrict__ cursor, int N) {
    int i = blockIdx.x * 256 + threadIdx.x;
    if (i >= N) return;
    int s = pre[i] + boff[blockIdx.x];
    starts[i] = s;
    cursor[i] = s;
}

// ---- 3. scatter edges into CSR buckets as packed (row, norm) 8B records ----
__global__ void k_scatter(const int* __restrict__ row, const int* __restrict__ col,
                          const float* __restrict__ ew, const float* __restrict__ dis,
                          int* __restrict__ cursor, ull* __restrict__ sedge, int E) {
    int e = blockIdx.x * blockDim.x + threadIdx.x;
    if (e >= E) return;
    int r = row[e], c = col[e];
    float nr = dis[r] * ew[e] * dis[c];
    int pos = atomicAdd(&cursor[c], 1);
    sedge[pos] = ((ull)(unsigned)r << 32) | (ull)__float_as_uint(nr);
}

// ---- 4. gather pass 1 + fused 1->64->1 MLP fold -> t ----
__global__ void k_gather1(const int* __restrict__ starts, const ull* __restrict__ sedge,
                          const float* __restrict__ xT, const float* __restrict__ dis,
                          const float* __restrict__ W1, const float* __restrict__ b1,
                          const float* __restrict__ W2, const float* __restrict__ b2,
                          float* __restrict__ t, int N) {
    int i = blockIdx.x * blockDim.x + threadIdx.x;
    if (i >= N * BATCH) return;
    int n = i >> 3, b = i & 7;
    float s = 0.0f;
    int e1 = starts[n + 1];
    for (int j = starts[n]; j < e1; ++j) {
        ull v = sedge[j];
        int r = (int)(v >> 32);
        float nr = __uint_as_float((unsigned)v);
        s = fmaf(nr, xT[(r << 3) + b], s);
    }
    float di = dis[n];
    s = fmaf(di * di, xT[i], s);          // self-loop
    float acc = 0.0f;
#pragma unroll
    for (int f = 0; f < HIDDEN; ++f) {
        float h = fmaf(s, W1[f], b1[f]);
        acc = fmaf(fmaxf(h, 0.0f), W2[f], acc);
    }
    t[i] = acc;
}

// ---- 5. gather pass 2 + fused epilogue -> out [B][N] ----
__global__ void k_gather2(const int* __restrict__ starts, const ull* __restrict__ sedge,
                          const float* __restrict__ t, const float* __restrict__ xT,
                          const float* __restrict__ dis, const float* __restrict__ b2,
                          float* __restrict__ out, int N) {
    int i = blockIdx.x * blockDim.x + threadIdx.x;
    if (i >= N * BATCH) return;
    int n = i >> 3, b = i & 7;
    float g = 0.0f;
    int e1 = starts[n + 1];
    for (int j = starts[n]; j < e1; ++j) {
        ull v = sedge[j];
        int r = (int)(v >> 32);
        float nr = __uint_as_float((unsigned)v);
        g = fmaf(nr, t[(r << 3) + b], g);
    }
    float di = dis[n];
    g = fmaf(di * di, t[i], g);           // self-loop
    out[b * N + n] = xT[i] + 0.5f * (b2[0] + g);
}

// ---------------- launch ----------------
extern "C" void kernel_launch(void* const* d_in, const int* in_sizes, int n_in,
                              void* d_out, int out_size, void* d_ws, size_t ws_size,
                              hipStream_t stream) {
    const float* x  = (const float*)d_in[0];
    const int*   ei = (const int*)d_in[1];      // [2, E] int32
    const float* ew = (const float*)d_in[2];
    const float* W1 = (const float*)d_in[3];
    const float* b1 = (const float*)d_in[4];
    const float* W2 = (const float*)d_in[5];
    const float* b2 = (const float*)d_in[6];
    float* out = (float*)d_out;

    const int N = N_NODES, E = N_EDGES;
    const int* row = ei;
    const int* col = ei + E;

    // workspace layout (8B-aligned chunks first)
    ull*   packed = (ull*)d_ws;                  // N ull (zeroed by k_zero)
    ull*   sedge  = packed + N;                  // E ull
    float* xT     = (float*)(sedge + E);         // N*BATCH (16B aligned)
    float* t      = xT + N * BATCH;              // N*BATCH
    int*   pre    = (int*)(t + N * BATCH);       // N
    int*   bsum   = pre + N;                     // 128
    int*   boff   = bsum + 128;                  // 128
    int*   starts = boff + 128;                  // N+1
    int*   cursor = starts + N + 1;              // N
    float* dis    = (float*)(cursor + N);        // N

    const int BS = 256;
    int gE  = (E + BS - 1) / BS;
    int gBN = (N * BATCH + BS - 1) / BS;

    k_zero   <<<NB_SCAN, 256, 0, stream>>>(packed, N);
    k_hist   <<<gE,      BS,  0, stream>>>(col, ew, packed, E);
    k_scan1  <<<NB_SCAN, 256, 0, stream>>>(packed, pre, bsum, dis, x, xT, N);
    k_scan2  <<<1,       128, 0, stream>>>(bsum, boff, starts);
    k_scan3  <<<NB_SCAN, 256, 0, stream>>>(pre, boff, starts, cursor, N);
    k_scatter<<<gE,      BS,  0, stream>>>(row, col, ew, dis, cursor, sedge, E);
    k_gather1<<<gBN,     BS,  0, stream>>>(starts, sedge, xT, dis, W1, b1, W2, b2, t, N);
    k_gather2<<<gBN,     BS,  0, stream>>>(starts, sedge, t, xT, dis, b2, out, N);
}

// Round 6
// 102.231 us; speedup vs baseline: 5.5069x; 1.1370x over previous
//
#include <hip/hip_runtime.h>

#define N_NODES 20000
#define N_EDGES 640000
#define HIDDEN  64
#define BATCH   8
#define NB_SCAN ((N_NODES + 255) / 256)   // 79 blocks

typedef unsigned long long ull;

__device__ inline int wave_iscan(int v, int lane) {
#pragma unroll
    for (int off = 1; off < 64; off <<= 1) {
        int u = __shfl_up(v, off, 64);
        if (lane >= off) v += u;
    }
    return v;
}

// ---- 0. zero the histogram accumulator ----
__global__ void k_zero(ull* __restrict__ packed, int N) {
    int i = blockIdx.x * blockDim.x + threadIdx.x;
    if (i < N) packed[i] = 0ULL;
}

// ---- 1. histogram: packed[col] += (1<<40) | fx(ew)  (count | fixed-point deg) ----
__global__ void k_hist(const int* __restrict__ col, const float* __restrict__ ew,
                       ull* __restrict__ packed, int E) {
    int e = blockIdx.x * blockDim.x + threadIdx.x;
    if (e >= E) return;
    int c = col[e];
    ull fx = (ull)(ew[e] * 16777216.0f + 0.5f); // 2^24 fixed point
    atomicAdd(&packed[c], (1ULL << 40) | fx);
}

// ---- 2a. per-block exclusive scan of counts; dis = rsqrt(deg+1); fused x->xT transpose ----
__global__ void k_scan1(const ull* __restrict__ packed,
                        int* __restrict__ pre, int* __restrict__ bsum,
                        float* __restrict__ dis,
                        const float* __restrict__ x, float* __restrict__ xT, int N) {
    int tid = threadIdx.x;
    int i = blockIdx.x * 256 + tid;
    int lane = tid & 63, wid = tid >> 6;
    ull p = (i < N) ? packed[i] : 0ULL;
    int v = (int)(p >> 40);
    if (i < N) {
        float deg = (float)(p & 0xFFFFFFFFFFULL) * 5.9604644775390625e-8f; // 2^-24
        dis[i] = rsqrtf(deg + 1.0f);
        float4 lo, hi;
        lo.x = x[0 * N + i]; lo.y = x[1 * N + i]; lo.z = x[2 * N + i]; lo.w = x[3 * N + i];
        hi.x = x[4 * N + i]; hi.y = x[5 * N + i]; hi.z = x[6 * N + i]; hi.w = x[7 * N + i];
        ((float4*)xT)[i * 2]     = lo;
        ((float4*)xT)[i * 2 + 1] = hi;
    }
    int incl = wave_iscan(v, lane);
    __shared__ int ws[4];
    if (lane == 63) ws[wid] = incl;
    __syncthreads();
    if (tid == 0) {
        int r = 0;
#pragma unroll
        for (int w = 0; w < 4; ++w) { int s = ws[w]; ws[w] = r; r += s; }
    }
    __syncthreads();
    int excl = incl - v + ws[wid];
    if (i < N) pre[i] = excl;
    if (tid == 255) bsum[blockIdx.x] = excl + v;   // block total
}

// ---- 2b. add block offsets (each block sums its own bsum prefix) -> starts, cursor ----
__global__ void k_scan3(const int* __restrict__ pre, const int* __restrict__ bsum,
                        int* __restrict__ starts, int* __restrict__ cursor, int N) {
    __shared__ int offs;
    int tid = threadIdx.x;
    if (tid < 64) {
        int v = 0;
        if (tid < blockIdx.x) v = bsum[tid];
        int t2 = tid + 64;
        if (t2 < blockIdx.x) v += bsum[t2];
#pragma unroll
        for (int m = 1; m < 64; m <<= 1) v += __shfl_xor(v, m, 64);
        if (tid == 0) offs = v;
    }
    __syncthreads();
    int i = blockIdx.x * 256 + tid;
    if (i < N) { int s = pre[i] + offs; starts[i] = s; cursor[i] = s; }
    if (blockIdx.x == 0 && tid == 0) starts[N_NODES] = N_EDGES;
}

// ---- 3. scatter edges into CSR buckets as packed (row, norm) 8B records ----
__global__ void k_scatter(const int* __restrict__ row, const int* __restrict__ col,
                          const float* __restrict__ ew, const float* __restrict__ dis,
                          int* __restrict__ cursor, ull* __restrict__ sedge, int E) {
    int e = blockIdx.x * blockDim.x + threadIdx.x;
    if (e >= E) return;
    int r = row[e], c = col[e];
    float nr = dis[r] * ew[e] * dis[c];
    int pos = atomicAdd(&cursor[c], 1);
    sedge[pos] = ((ull)(unsigned)r << 32) | (ull)__float_as_uint(nr);
}

// ---- 4. gather pass 1 (split-K=4) + distributed MLP fold -> t ----
// thread i: node n = i>>5, chunk k = (i>>3)&3, batch b = i&7
__global__ void k_gather1(const int* __restrict__ starts, const ull* __restrict__ sedge,
                          const float* __restrict__ xT, const float* __restrict__ dis,
                          const float* __restrict__ W1, const float* __restrict__ b1,
                          const float* __restrict__ W2, const float* __restrict__ b2,
                          float* __restrict__ t, int N) {
    int i = blockIdx.x * blockDim.x + threadIdx.x;
    if (i >= N * 32) return;
    int n = i >> 5;
    int w = i & 31, k = w >> 3, b = w & 7;
    int e0 = starts[n], e1 = starts[n + 1], len = e1 - e0;
    int j0 = e0 + ((len * k) >> 2);
    int j1 = e0 + ((len * (k + 1)) >> 2);
    float s = 0.0f;
    for (int j = j0; j < j1; ++j) {
        ull v = sedge[j];
        s = fmaf(__uint_as_float((unsigned)v), xT[((int)(v >> 32) << 3) + b], s);
    }
    // combine the 4 chunks (lanes xor 8, 16 stay within the 32-lane node group)
    s += __shfl_xor(s, 8, 64);
    s += __shfl_xor(s, 16, 64);
    float di = dis[n];
    s = fmaf(di * di, xT[(n << 3) + b], s);     // self-loop (all copies identical)
    // distributed MLP: each k-lane folds 16 hidden units, then combine
    float acc = 0.0f;
#pragma unroll
    for (int ff = 0; ff < 16; ++ff) {
        int f = (k << 4) + ff;
        float h = fmaf(s, W1[f], b1[f]);
        acc = fmaf(fmaxf(h, 0.0f), W2[f], acc);
    }
    acc += __shfl_xor(acc, 8, 64);
    acc += __shfl_xor(acc, 16, 64);
    if (k == 0) t[(n << 3) + b] = acc;
}

// ---- 5. gather pass 2 (split-K=4) + fused epilogue -> out [B][N] ----
__global__ void k_gather2(const int* __restrict__ starts, const ull* __restrict__ sedge,
                          const float* __restrict__ t, const float* __restrict__ xT,
                          const float* __restrict__ dis, const float* __restrict__ b2,
                          float* __restrict__ out, int N) {
    int i = blockIdx.x * blockDim.x + threadIdx.x;
    if (i >= N * 32) return;
    int n = i >> 5;
    int w = i & 31, k = w >> 3, b = w & 7;
    int e0 = starts[n], e1 = starts[n + 1], len = e1 - e0;
    int j0 = e0 + ((len * k) >> 2);
    int j1 = e0 + ((len * (k + 1)) >> 2);
    float g = 0.0f;
    for (int j = j0; j < j1; ++j) {
        ull v = sedge[j];
        g = fmaf(__uint_as_float((unsigned)v), t[((int)(v >> 32) << 3) + b], g);
    }
    g += __shfl_xor(g, 8, 64);
    g += __shfl_xor(g, 16, 64);
    if (k == 0) {
        float di = dis[n];
        g = fmaf(di * di, t[(n << 3) + b], g);   // self-loop
        out[b * N + n] = xT[(n << 3) + b] + 0.5f * (b2[0] + g);
    }
}

// ---------------- launch ----------------
extern "C" void kernel_launch(void* const* d_in, const int* in_sizes, int n_in,
                              void* d_out, int out_size, void* d_ws, size_t ws_size,
                              hipStream_t stream) {
    const float* x  = (const float*)d_in[0];
    const int*   ei = (const int*)d_in[1];      // [2, E] int32
    const float* ew = (const float*)d_in[2];
    const float* W1 = (const float*)d_in[3];
    const float* b1 = (const float*)d_in[4];
    const float* W2 = (const float*)d_in[5];
    const float* b2 = (const float*)d_in[6];
    float* out = (float*)d_out;

    const int N = N_NODES, E = N_EDGES;
    const int* row = ei;
    const int* col = ei + E;

    // workspace layout (8B-aligned chunks first)
    ull*   packed = (ull*)d_ws;                  // N ull (zeroed by k_zero)
    ull*   sedge  = packed + N;                  // E ull
    float* xT     = (float*)(sedge + E);         // N*BATCH (16B aligned)
    float* t      = xT + N * BATCH;              // N*BATCH
    int*   pre    = (int*)(t + N * BATCH);       // N
    int*   bsum   = pre + N;                     // 128
    int*   starts = bsum + 128;                  // N+1
    int*   cursor = starts + N + 1;              // N
    float* dis    = (float*)(cursor + N);        // N

    const int BS = 256;
    int gE  = (E + BS - 1) / BS;
    int gS  = (N * 32 + BS - 1) / BS;            // 2500 blocks for split-K gathers

    k_zero   <<<NB_SCAN, 256, 0, stream>>>(packed, N);
    k_hist   <<<gE,      BS,  0, stream>>>(col, ew, packed, E);
    k_scan1  <<<NB_SCAN, 256, 0, stream>>>(packed, pre, bsum, dis, x, xT, N);
    k_scan3  <<<NB_SCAN, 256, 0, stream>>>(pre, bsum, starts, cursor, N);
    k_scatter<<<gE,      BS,  0, stream>>>(row, col, ew, dis, cursor, sedge, E);
    k_gather1<<<gS,      BS,  0, stream>>>(starts, sedge, xT, dis, W1, b1, W2, b2, t, N);
    k_gather2<<<gS,      BS,  0, stream>>>(starts, sedge, t, xT, dis, b2, out, N);
}